// Round 1
// baseline (5150.142 us; speedup 1.0000x reference)
//
#include <hip/hip_runtime.h>
#include <math.h>

#define NEGF (-1e30f)

__device__ __forceinline__ float gelu_exact(float x) {
  // jax.nn.gelu(approximate=False): x * 0.5 * (1 + erf(x/sqrt(2)))
  return 0.5f * x * (1.0f + erff(x * 0.70710678118654752440f));
}

// ---------------------------------------------------------------------------
// GEMM: out(M,NC) = A(M,K) @ W(K,NC) + bias, EPI: 0 = bias only, 1 = bias+gelu
// Block: 16 rows x NC cols, NC/4 threads, each thread owns 4 contiguous cols.
// W streamed from global (L2-resident: <=3 MB), A tile staged in LDS.
// ---------------------------------------------------------------------------
template<int NC, int EPI>
__global__ __launch_bounds__(NC/4) void gemm_kernel(
    const float* __restrict__ A, const float* __restrict__ W,
    const float* __restrict__ bias, float* __restrict__ out,
    long M, int K)
{
  constexpr int THREADS = NC / 4;
  __shared__ float As[16][32];
  const int tid = threadIdx.x;
  const int c0 = tid * 4;
  const long row0 = (long)blockIdx.x * 16;

  float4 acc[16];
#pragma unroll
  for (int r = 0; r < 16; ++r) acc[r] = make_float4(0.f, 0.f, 0.f, 0.f);

  for (int k0 = 0; k0 < K; k0 += 32) {
    // stage A tile (16x32) as float4s
    for (int idx = tid; idx < 16 * 8; idx += THREADS) {
      int r = idx >> 3, kk = (idx & 7) << 2;
      long row = row0 + r;
      float4 av = (row < M) ? *(const float4*)&A[row * K + k0 + kk]
                            : make_float4(0.f, 0.f, 0.f, 0.f);
      *(float4*)&As[r][kk] = av;
    }
    __syncthreads();
#pragma unroll 2
    for (int kk = 0; kk < 32; kk += 4) {
      float4 w0 = *(const float4*)&W[(long)(k0 + kk + 0) * NC + c0];
      float4 w1 = *(const float4*)&W[(long)(k0 + kk + 1) * NC + c0];
      float4 w2 = *(const float4*)&W[(long)(k0 + kk + 2) * NC + c0];
      float4 w3 = *(const float4*)&W[(long)(k0 + kk + 3) * NC + c0];
#pragma unroll
      for (int r = 0; r < 16; ++r) {
        float4 a = *(const float4*)&As[r][kk];  // broadcast read
        acc[r].x = fmaf(a.x,w0.x,fmaf(a.y,w1.x,fmaf(a.z,w2.x,fmaf(a.w,w3.x,acc[r].x))));
        acc[r].y = fmaf(a.x,w0.y,fmaf(a.y,w1.y,fmaf(a.z,w2.y,fmaf(a.w,w3.y,acc[r].y))));
        acc[r].z = fmaf(a.x,w0.z,fmaf(a.y,w1.z,fmaf(a.z,w2.z,fmaf(a.w,w3.z,acc[r].z))));
        acc[r].w = fmaf(a.x,w0.w,fmaf(a.y,w1.w,fmaf(a.z,w2.w,fmaf(a.w,w3.w,acc[r].w))));
      }
    }
    __syncthreads();
  }

  float4 b4 = *(const float4*)&bias[c0];
#pragma unroll
  for (int r = 0; r < 16; ++r) {
    long row = row0 + r;
    if (row >= M) continue;
    float4 v = acc[r];
    v.x += b4.x; v.y += b4.y; v.z += b4.z; v.w += b4.w;
    if (EPI == 1) {
      v.x = gelu_exact(v.x); v.y = gelu_exact(v.y);
      v.z = gelu_exact(v.z); v.w = gelu_exact(v.w);
    }
    *(float4*)&out[row * NC + c0] = v;
  }
}

// ---------------------------------------------------------------------------
// LayerNorm in place, one wave per row (D = 768 -> 12 elems/lane)
// ---------------------------------------------------------------------------
template<int D>
__global__ __launch_bounds__(256) void ln_kernel(
    float* __restrict__ X, const float* __restrict__ g,
    const float* __restrict__ bt, long M)
{
  constexpr int NPL = D / 64;
  const int lane = threadIdx.x & 63;
  const int wid = threadIdx.x >> 6;
  const long row = (long)blockIdx.x * 4 + wid;
  if (row >= M) return;

  float v[NPL];
  float s = 0.f;
#pragma unroll
  for (int i = 0; i < NPL; ++i) { v[i] = X[row * D + i * 64 + lane]; s += v[i]; }
#pragma unroll
  for (int off = 32; off; off >>= 1) s += __shfl_xor(s, off);
  const float mu = s * (1.0f / D);
  float q = 0.f;
#pragma unroll
  for (int i = 0; i < NPL; ++i) { float d = v[i] - mu; q += d * d; }
#pragma unroll
  for (int off = 32; off; off >>= 1) q += __shfl_xor(q, off);
  const float rs = rsqrtf(q * (1.0f / D) + 1e-6f);
#pragma unroll
  for (int i = 0; i < NPL; ++i) {
    int c = i * 64 + lane;
    X[row * D + c] = (v[i] - mu) * rs * g[c] + bt[c];
  }
}

// ---------------------------------------------------------------------------
// GEMM3 + bias + log_softmax + gather-to-extended-labels, fused.
// Block: 16 rows x V(=1024) cols, 256 threads x 4 cols.
// smem (exactly 64 KB) aliased: A-tile (main loop) -> red buf -> lp scores.
// ---------------------------------------------------------------------------
template<int V>
__global__ __launch_bounds__(V/4) void gemm3_softmax_kernel(
    const float* __restrict__ A, const float* __restrict__ W,
    const float* __restrict__ bias, const int* __restrict__ targets,
    float* __restrict__ lp_ext, long M, int K, int B, int L, int S)
{
  constexpr int THREADS = V / 4;
  __shared__ float smem[16 * V];  // 64 KB
  const int tid = threadIdx.x;
  const int c0 = tid * 4;
  const long row0 = (long)blockIdx.x * 16;

  float4 acc[16];
#pragma unroll
  for (int r = 0; r < 16; ++r) acc[r] = make_float4(0.f, 0.f, 0.f, 0.f);

  for (int k0 = 0; k0 < K; k0 += 32) {
    for (int idx = tid; idx < 16 * 8; idx += THREADS) {
      int r = idx >> 3, kk = (idx & 7) << 2;
      long row = row0 + r;
      float4 av = (row < M) ? *(const float4*)&A[row * K + k0 + kk]
                            : make_float4(0.f, 0.f, 0.f, 0.f);
      *(float4*)&smem[r * 32 + kk] = av;
    }
    __syncthreads();
#pragma unroll 2
    for (int kk = 0; kk < 32; kk += 4) {
      float4 w0 = *(const float4*)&W[(long)(k0 + kk + 0) * V + c0];
      float4 w1 = *(const float4*)&W[(long)(k0 + kk + 1) * V + c0];
      float4 w2 = *(const float4*)&W[(long)(k0 + kk + 2) * V + c0];
      float4 w3 = *(const float4*)&W[(long)(k0 + kk + 3) * V + c0];
#pragma unroll
      for (int r = 0; r < 16; ++r) {
        float4 a = *(const float4*)&smem[r * 32 + kk];
        acc[r].x = fmaf(a.x,w0.x,fmaf(a.y,w1.x,fmaf(a.z,w2.x,fmaf(a.w,w3.x,acc[r].x))));
        acc[r].y = fmaf(a.x,w0.y,fmaf(a.y,w1.y,fmaf(a.z,w2.y,fmaf(a.w,w3.y,acc[r].y))));
        acc[r].z = fmaf(a.x,w0.z,fmaf(a.y,w1.z,fmaf(a.z,w2.z,fmaf(a.w,w3.z,acc[r].z))));
        acc[r].w = fmaf(a.x,w0.w,fmaf(a.y,w1.w,fmaf(a.z,w2.w,fmaf(a.w,w3.w,acc[r].w))));
      }
    }
    __syncthreads();
  }

  // bias
  float4 b4 = *(const float4*)&bias[c0];
#pragma unroll
  for (int r = 0; r < 16; ++r) {
    acc[r].x += b4.x; acc[r].y += b4.y; acc[r].z += b4.z; acc[r].w += b4.w;
  }

  const int lane = tid & 63, wid = tid >> 6;
  float rmax[16], rsum[16];
#pragma unroll
  for (int r = 0; r < 16; ++r)
    rmax[r] = fmaxf(fmaxf(acc[r].x, acc[r].y), fmaxf(acc[r].z, acc[r].w));
#pragma unroll
  for (int off = 1; off < 64; off <<= 1) {
#pragma unroll
    for (int r = 0; r < 16; ++r)
      rmax[r] = fmaxf(rmax[r], __shfl_xor(rmax[r], off));
  }
  if (lane == 0) {
#pragma unroll
    for (int r = 0; r < 16; ++r) smem[r * 4 + wid] = rmax[r];
  }
  __syncthreads();
#pragma unroll
  for (int r = 0; r < 16; ++r)
    rmax[r] = fmaxf(fmaxf(smem[r * 4 + 0], smem[r * 4 + 1]),
                    fmaxf(smem[r * 4 + 2], smem[r * 4 + 3]));
  __syncthreads();
#pragma unroll
  for (int r = 0; r < 16; ++r) {
    rsum[r] = expf(acc[r].x - rmax[r]) + expf(acc[r].y - rmax[r]) +
              expf(acc[r].z - rmax[r]) + expf(acc[r].w - rmax[r]);
  }
#pragma unroll
  for (int off = 1; off < 64; off <<= 1) {
#pragma unroll
    for (int r = 0; r < 16; ++r) rsum[r] += __shfl_xor(rsum[r], off);
  }
  if (lane == 0) {
#pragma unroll
    for (int r = 0; r < 16; ++r) smem[r * 4 + wid] = rsum[r];
  }
  __syncthreads();
#pragma unroll
  for (int r = 0; r < 16; ++r) {
    float tot = smem[r * 4 + 0] + smem[r * 4 + 1] + smem[r * 4 + 2] + smem[r * 4 + 3];
    rmax[r] = rmax[r] + logf(tot);  // rmax now holds logZ
  }
  __syncthreads();
  // write lp = score - logZ into smem (full 16x1024)
#pragma unroll
  for (int r = 0; r < 16; ++r) {
    float4 v;
    v.x = acc[r].x - rmax[r]; v.y = acc[r].y - rmax[r];
    v.z = acc[r].z - rmax[r]; v.w = acc[r].w - rmax[r];
    *(float4*)&smem[r * V + c0] = v;
  }
  __syncthreads();
  // gather extended labels: lp_ext[m*S + s] = lp[row m][ext(b,s)]
  const int tot = 16 * S;
  for (int idx = tid; idx < tot; idx += THREADS) {
    int r = idx / S;
    int s = idx - r * S;
    long m = row0 + r;
    if (m < M) {
      int bb = (int)(m % B);
      int lab = (s & 1) ? targets[bb * L + (s >> 1)] : 0;
      lp_ext[m * (long)S + s] = smem[r * V + lab];
    }
  }
}

// ---------------------------------------------------------------------------
// CTC forward scan: one block per batch element, one thread per lattice state.
// ---------------------------------------------------------------------------
__global__ __launch_bounds__(512) void ctc_kernel(
    const float* __restrict__ lp,  // (T,B,S) flattened: [ (t*B+b)*S + s ]
    const int* __restrict__ targets, const int* __restrict__ inlens,
    const int* __restrict__ tlens, float* __restrict__ partial,
    int T, int B, int L, int S)
{
  __shared__ float al[2][512];
  __shared__ float lb_sh, ll_sh;
  const int b = blockIdx.x;
  const int s = threadIdx.x;
  const int inlen = inlens[b];
  const int tlen = tlens[b];
  const int send = 2 * tlen;
  if (threadIdx.x == 0) { lb_sh = NEGF; ll_sh = NEGF; }
  const bool active = (s < S);

  int lab = 0;
  bool skip = false;
  if (active && (s & 1)) {
    lab = targets[b * L + (s >> 1)];
    if (s >= 3) skip = (lab != 0) && (lab != targets[b * L + (s >> 1) - 1]);
  }
  const float* lpb = lp + (long)b * S;
  const long strideT = (long)B * S;

  if (active) {
    float v0 = (s <= 1) ? lpb[s] : NEGF;
    al[0][s] = v0;
    if (inlen == 1) {
      if (s == send) lb_sh = v0;
      else if (s == send - 1) ll_sh = v0;
    }
  }
  __syncthreads();

  int p = 0;
  for (int t = 1; t < T; ++t) {
    if (active) {
      float a0 = al[p][s];
      float a1 = (s >= 1) ? al[p][s - 1] : NEGF;
      float a2 = skip ? al[p][s - 2] : NEGF;
      float m = fmaxf(a0, fmaxf(a1, a2));
      float sum = expf(a0 - m) + expf(a1 - m) + expf(a2 - m);
      float nv = m + logf(sum) + lpb[(long)t * strideT + s];
      al[p ^ 1][s] = nv;
      if (t == inlen - 1) {
        if (s == send) lb_sh = nv;
        else if (s == send - 1) ll_sh = nv;
      }
    }
    p ^= 1;
    __syncthreads();
  }

  if (threadIdx.x == 0) {
    float lb = lb_sh, ll = ll_sh;
    float mx = fmaxf(lb, ll);
    float loss = -(mx + logf(expf(lb - mx) + expf(ll - mx)));
    if (!(loss <= 1e29f)) loss = 0.f;  // zero_infinity (also catches NaN)
    partial[b] = loss / (float)tlen;
  }
}

__global__ void reduce_kernel(const float* __restrict__ partial,
                              float* __restrict__ out, int B)
{
  int lane = threadIdx.x;
  float v = (lane < B) ? partial[lane] : 0.f;
#pragma unroll
  for (int off = 32; off; off >>= 1) v += __shfl_xor(v, off);
  if (lane == 0) out[0] = v / (float)B;
}

// ---------------------------------------------------------------------------
extern "C" void kernel_launch(void* const* d_in, const int* in_sizes, int n_in,
                              void* d_out, int out_size, void* d_ws, size_t ws_size,
                              hipStream_t stream) {
  const float* enc = (const float*)d_in[0];
  const float* Wp  = (const float*)d_in[1];
  const float* bp  = (const float*)d_in[2];
  const float* Wt  = (const float*)d_in[3];
  const float* btr = (const float*)d_in[4];
  const float* lng = (const float*)d_in[5];
  const float* lnb = (const float*)d_in[6];
  const float* Wd  = (const float*)d_in[7];
  const float* bd  = (const float*)d_in[8];
  const int* tgt   = (const int*)d_in[9];
  const int* inl   = (const int*)d_in[10];
  const int* tll   = (const int*)d_in[11];

  const int D = in_sizes[2];              // 768
  const int B = in_sizes[10];             // 32
  const int L = in_sizes[9] / B;          // 150
  const long M = (long)in_sizes[0] / D;   // T*B = 64000
  const int T = (int)(M / B);             // 2000
  const int S = 2 * L + 1;                // 301

  char* wsb = (char*)d_ws;
  const size_t szMD = (size_t)M * D * sizeof(float);
  float* X1 = (float*)wsb;
  float* X2 = (float*)(wsb + szMD);
  float* LP = (float*)(wsb + 2 * szMD);
  float* partial = (float*)(wsb + 2 * szMD + (size_t)M * S * sizeof(float));

  const int grid = (int)((M + 15) / 16);
  gemm_kernel<768, 0><<<grid, 192, 0, stream>>>(enc, Wp, bp, X1, M, D);
  gemm_kernel<768, 1><<<grid, 192, 0, stream>>>(X1, Wt, btr, X2, M, D);
  ln_kernel<768><<<(int)((M + 3) / 4), 256, 0, stream>>>(X2, lng, lnb, M);
  gemm3_softmax_kernel<1024><<<grid, 256, 0, stream>>>(X2, Wd, bd, tgt, LP, M, D, B, L, S);
  const int cthreads = ((S + 63) / 64) * 64;
  ctc_kernel<<<B, cthreads, 0, stream>>>(LP, tgt, inl, tll, partial, T, B, L, S);
  reduce_kernel<<<1, 64, 0, stream>>>(partial, (float*)d_out, B);
}

// Round 2
// 1759.113 us; speedup vs baseline: 2.9277x; 2.9277x over previous
//
#include <hip/hip_runtime.h>
#include <hip/hip_bf16.h>
#include <math.h>

#define NEGF (-1e30f)

typedef short bf16x8 __attribute__((ext_vector_type(8)));
typedef float f32x4 __attribute__((ext_vector_type(4)));

__device__ __forceinline__ unsigned short f2b(float x) {
  __hip_bfloat16 h = __float2bfloat16(x);
  return *reinterpret_cast<unsigned short*>(&h);
}
__device__ __forceinline__ float b2f(unsigned short u) {
  __hip_bfloat16 h;
  *reinterpret_cast<unsigned short*>(&h) = u;
  return __bfloat162float(h);
}
__device__ __forceinline__ float gelu_exact(float x) {
  return 0.5f * x * (1.0f + erff(x * 0.70710678118654752440f));
}

// ---------------------------------------------------------------------------
// fp32 -> bf16 elementwise (vectorized float4 -> 4x bf16)
// ---------------------------------------------------------------------------
__global__ __launch_bounds__(256) void cvt_enc_kernel(
    const float* __restrict__ in, unsigned short* __restrict__ out, long n4)
{
  long i = (long)blockIdx.x * blockDim.x + threadIdx.x;
  const long stride = (long)gridDim.x * blockDim.x;
  for (; i < n4; i += stride) {
    float4 v = ((const float4*)in)[i];
    ushort4 o;
    o.x = f2b(v.x); o.y = f2b(v.y); o.z = f2b(v.z); o.w = f2b(v.w);
    ((ushort4*)out)[i] = o;
  }
}

// ---------------------------------------------------------------------------
// W (K,N) fp32 -> WT (N,K) bf16, 32x32 LDS tile transpose
// ---------------------------------------------------------------------------
__global__ __launch_bounds__(256) void cvt_wt_kernel(
    const float* __restrict__ W, unsigned short* __restrict__ WT, int K, int N)
{
  __shared__ float tile[32][33];
  const int n0 = blockIdx.x * 32, k0 = blockIdx.y * 32;
  const int tx = threadIdx.x, ty = threadIdx.y;  // 32 x 8
#pragma unroll
  for (int i = 0; i < 32; i += 8) {
    int k = k0 + ty + i, n = n0 + tx;
    tile[ty + i][tx] = (k < K && n < N) ? W[(long)k * N + n] : 0.f;
  }
  __syncthreads();
#pragma unroll
  for (int i = 0; i < 32; i += 8) {
    int n = n0 + ty + i, k = k0 + tx;
    if (n < N && k < K) WT[(long)n * K + k] = f2b(tile[tx][ty + i]);
  }
}

// ---------------------------------------------------------------------------
// Unified bf16 MFMA GEMM: out(M,N) = A(M,K) @ WT(N,K)^T + bias [; gelu]
// Block: 32 rows x N cols, 8 waves; wave owns NT*16 cols, 2 m-tiles.
// A strip staged in LDS (padded, conflict-free b128); B streamed from L2.
// EPI: 0 = bias, 1 = bias + gelu. bf16 output, repacked via LDS for
// coalesced stores.
// ---------------------------------------------------------------------------
template<int K, int NT, int EPI>
__global__ __launch_bounds__(512, 4) void gemm_bf16_kernel(
    const unsigned short* __restrict__ A, const unsigned short* __restrict__ WT,
    const float* __restrict__ bias, unsigned short* __restrict__ out, long M)
{
  constexpr int KP = K + 8;
  constexpr int N = NT * 8 * 16;
  extern __shared__ char smem[];
  unsigned short* as = (unsigned short*)smem;  // [32][KP]
  const int tid = threadIdx.x;
  const int lane = tid & 63;
  const int w = tid >> 6;
  const int cl = lane & 15, g = lane >> 4;
  const long row0 = (long)blockIdx.x * 32;
  const int n_base = w * (NT * 16);

  // stage A strip (32 x K), coalesced 16B chunks
  constexpr int CH = 32 * (K / 8);
  for (int c = tid; c < CH; c += 512) {
    int r = c / (K / 8);
    int kc = (c % (K / 8)) * 8;
    long row = row0 + r;
    bf16x8 v = {0, 0, 0, 0, 0, 0, 0, 0};
    if (row < M) v = *(const bf16x8*)&A[row * K + kc];
    *(bf16x8*)&as[r * KP + kc] = v;
  }
  __syncthreads();

  f32x4 acc[2][NT];
#pragma unroll
  for (int mt = 0; mt < 2; ++mt)
#pragma unroll
    for (int nt = 0; nt < NT; ++nt) acc[mt][nt] = (f32x4){0.f, 0.f, 0.f, 0.f};

  const int aoff = cl * KP + g * 8;
  const unsigned short* bptr = WT + (long)(n_base + cl) * K + g * 8;

  for (int kk = 0; kk < K; kk += 32) {
    bf16x8 a0 = *(const bf16x8*)&as[aoff + kk];
    bf16x8 a1 = *(const bf16x8*)&as[aoff + 16 * KP + kk];
    bf16x8 b[NT];
#pragma unroll
    for (int nt = 0; nt < NT; ++nt)
      b[nt] = *(const bf16x8*)&bptr[(long)nt * 16 * K + kk];
#pragma unroll
    for (int nt = 0; nt < NT; ++nt) {
      acc[0][nt] = __builtin_amdgcn_mfma_f32_16x16x32_bf16(a0, b[nt], acc[0][nt], 0, 0, 0);
      acc[1][nt] = __builtin_amdgcn_mfma_f32_16x16x32_bf16(a1, b[nt], acc[1][nt], 0, 0, 0);
    }
  }

  float bv[NT];
#pragma unroll
  for (int nt = 0; nt < NT; ++nt) bv[nt] = bias[n_base + nt * 16 + cl];

  __syncthreads();  // A strip dead; reuse smem as repack buffer [32][N] bf16
  unsigned short* rb = (unsigned short*)smem;
#pragma unroll
  for (int mt = 0; mt < 2; ++mt)
#pragma unroll
    for (int nt = 0; nt < NT; ++nt)
#pragma unroll
      for (int j = 0; j < 4; ++j) {
        float v = acc[mt][nt][j] + bv[nt];
        if (EPI == 1) v = gelu_exact(v);
        rb[(mt * 16 + g * 4 + j) * N + n_base + nt * 16 + cl] = f2b(v);
      }
  __syncthreads();
  constexpr int CH2 = 32 * (N / 8);
  for (int c = tid; c < CH2; c += 512) {
    int r = c / (N / 8);
    long row = row0 + r;
    if (row < M) {
      int nc = (c % (N / 8)) * 8;
      *(bf16x8*)&out[row * N + nc] = *(const bf16x8*)&rb[r * N + nc];
    }
  }
}

// ---------------------------------------------------------------------------
// LayerNorm in place on bf16, one wave per row (D=768 -> 3x ushort4 per lane)
// ---------------------------------------------------------------------------
template<int D>
__global__ __launch_bounds__(256) void ln_bf16_kernel(
    unsigned short* __restrict__ X, const float* __restrict__ g,
    const float* __restrict__ bt, long M)
{
  constexpr int NI = D / 256;
  const int lane = threadIdx.x & 63;
  const int wid = threadIdx.x >> 6;
  const long row = (long)blockIdx.x * 4 + wid;
  if (row >= M) return;

  float v[NI * 4];
  float s = 0.f;
#pragma unroll
  for (int i = 0; i < NI; ++i) {
    ushort4 u = *(const ushort4*)&X[row * D + (i * 64 + lane) * 4];
    v[i * 4 + 0] = b2f(u.x); v[i * 4 + 1] = b2f(u.y);
    v[i * 4 + 2] = b2f(u.z); v[i * 4 + 3] = b2f(u.w);
    s += v[i * 4 + 0] + v[i * 4 + 1] + v[i * 4 + 2] + v[i * 4 + 3];
  }
#pragma unroll
  for (int off = 32; off; off >>= 1) s += __shfl_xor(s, off);
  const float mu = s * (1.0f / D);
  float q = 0.f;
#pragma unroll
  for (int i = 0; i < NI * 4; ++i) { float d = v[i] - mu; q += d * d; }
#pragma unroll
  for (int off = 32; off; off >>= 1) q += __shfl_xor(q, off);
  const float rs = rsqrtf(q * (1.0f / D) + 1e-6f);
#pragma unroll
  for (int i = 0; i < NI; ++i) {
    ushort4 o;
    int c = (i * 64 + lane) * 4;
    o.x = f2b((v[i * 4 + 0] - mu) * rs * g[c + 0] + bt[c + 0]);
    o.y = f2b((v[i * 4 + 1] - mu) * rs * g[c + 1] + bt[c + 1]);
    o.z = f2b((v[i * 4 + 2] - mu) * rs * g[c + 2] + bt[c + 2]);
    o.w = f2b((v[i * 4 + 3] - mu) * rs * g[c + 3] + bt[c + 3]);
    *(ushort4*)&X[row * D + c] = o;
  }
}

// ---------------------------------------------------------------------------
// GEMM3 (V=1024) + bias + log_softmax + gather to lp_ext, MFMA fused.
// Same main loop as gemm_bf16_kernel with NT=8; epilogue does row-softmax
// via shfl + small LDS, then two 16-row LDS passes for the label gather.
// ---------------------------------------------------------------------------
template<int K>
__global__ __launch_bounds__(512, 4) void gemm3_bf16_kernel(
    const unsigned short* __restrict__ A, const unsigned short* __restrict__ WT,
    const float* __restrict__ bias, const int* __restrict__ targets,
    float* __restrict__ lp_ext, long M, int B, int L, int S)
{
  constexpr int NT = 8, N = 1024, KP = K + 8;
  extern __shared__ char smem[];  // 65536: A strip, then redbuf/lpbuf
  unsigned short* as = (unsigned short*)smem;
  const int tid = threadIdx.x;
  const int lane = tid & 63;
  const int w = tid >> 6;
  const int cl = lane & 15, g = lane >> 4;
  const long row0 = (long)blockIdx.x * 32;
  const int n_base = w * (NT * 16);

  constexpr int CH = 32 * (K / 8);
  for (int c = tid; c < CH; c += 512) {
    int r = c / (K / 8);
    int kc = (c % (K / 8)) * 8;
    long row = row0 + r;
    bf16x8 v = {0, 0, 0, 0, 0, 0, 0, 0};
    if (row < M) v = *(const bf16x8*)&A[row * K + kc];
    *(bf16x8*)&as[r * KP + kc] = v;
  }
  __syncthreads();

  f32x4 acc[2][NT];
#pragma unroll
  for (int mt = 0; mt < 2; ++mt)
#pragma unroll
    for (int nt = 0; nt < NT; ++nt) acc[mt][nt] = (f32x4){0.f, 0.f, 0.f, 0.f};

  const int aoff = cl * KP + g * 8;
  const unsigned short* bptr = WT + (long)(n_base + cl) * K + g * 8;

  for (int kk = 0; kk < K; kk += 32) {
    bf16x8 a0 = *(const bf16x8*)&as[aoff + kk];
    bf16x8 a1 = *(const bf16x8*)&as[aoff + 16 * KP + kk];
    bf16x8 b[NT];
#pragma unroll
    for (int nt = 0; nt < NT; ++nt)
      b[nt] = *(const bf16x8*)&bptr[(long)nt * 16 * K + kk];
#pragma unroll
    for (int nt = 0; nt < NT; ++nt) {
      acc[0][nt] = __builtin_amdgcn_mfma_f32_16x16x32_bf16(a0, b[nt], acc[0][nt], 0, 0, 0);
      acc[1][nt] = __builtin_amdgcn_mfma_f32_16x16x32_bf16(a1, b[nt], acc[1][nt], 0, 0, 0);
    }
  }

  // bias in fp32
#pragma unroll
  for (int nt = 0; nt < NT; ++nt) {
    float bvv = bias[n_base + nt * 16 + cl];
#pragma unroll
    for (int mt = 0; mt < 2; ++mt)
#pragma unroll
      for (int j = 0; j < 4; ++j) acc[mt][nt][j] += bvv;
  }

  __syncthreads();  // all waves done reading A strip; smem now redbuf/lpbuf
  float* redbuf = (float*)smem;  // [8][32]

  // row max: in-register over nt, shfl over the 16-lane col group, LDS over waves
  float rmax[2][4];
#pragma unroll
  for (int mt = 0; mt < 2; ++mt)
#pragma unroll
    for (int j = 0; j < 4; ++j) {
      float m = acc[mt][0][j];
#pragma unroll
      for (int nt = 1; nt < NT; ++nt) m = fmaxf(m, acc[mt][nt][j]);
      rmax[mt][j] = m;
    }
#pragma unroll
  for (int off = 1; off < 16; off <<= 1)
#pragma unroll
    for (int mt = 0; mt < 2; ++mt)
#pragma unroll
      for (int j = 0; j < 4; ++j)
        rmax[mt][j] = fmaxf(rmax[mt][j], __shfl_xor(rmax[mt][j], off));
  if (cl == 0) {
#pragma unroll
    for (int mt = 0; mt < 2; ++mt)
#pragma unroll
      for (int j = 0; j < 4; ++j) redbuf[w * 32 + mt * 16 + g * 4 + j] = rmax[mt][j];
  }
  __syncthreads();
  float rowmax[2][4];
#pragma unroll
  for (int mt = 0; mt < 2; ++mt)
#pragma unroll
    for (int j = 0; j < 4; ++j) {
      float m = redbuf[0 * 32 + mt * 16 + g * 4 + j];
#pragma unroll
      for (int ww = 1; ww < 8; ++ww) m = fmaxf(m, redbuf[ww * 32 + mt * 16 + g * 4 + j]);
      rowmax[mt][j] = m;
    }
  __syncthreads();

  // row sum of exp
  float rsum[2][4];
#pragma unroll
  for (int mt = 0; mt < 2; ++mt)
#pragma unroll
    for (int j = 0; j < 4; ++j) {
      float s = 0.f;
#pragma unroll
      for (int nt = 0; nt < NT; ++nt) s += expf(acc[mt][nt][j] - rowmax[mt][j]);
      rsum[mt][j] = s;
    }
#pragma unroll
  for (int off = 1; off < 16; off <<= 1)
#pragma unroll
    for (int mt = 0; mt < 2; ++mt)
#pragma unroll
      for (int j = 0; j < 4; ++j) rsum[mt][j] += __shfl_xor(rsum[mt][j], off);
  if (cl == 0) {
#pragma unroll
    for (int mt = 0; mt < 2; ++mt)
#pragma unroll
      for (int j = 0; j < 4; ++j) redbuf[w * 32 + mt * 16 + g * 4 + j] = rsum[mt][j];
  }
  __syncthreads();
  float logz[2][4];
#pragma unroll
  for (int mt = 0; mt < 2; ++mt)
#pragma unroll
    for (int j = 0; j < 4; ++j) {
      float s = 0.f;
#pragma unroll
      for (int ww = 0; ww < 8; ++ww) s += redbuf[ww * 32 + mt * 16 + g * 4 + j];
      logz[mt][j] = rowmax[mt][j] + logf(s);
    }

  // two 16-row passes: write lp tile to LDS, gather extended labels
  float* lpbuf = (float*)smem;  // [16][1024] = 64 KB
  for (int h = 0; h < 2; ++h) {
    __syncthreads();
#pragma unroll
    for (int nt = 0; nt < NT; ++nt)
#pragma unroll
      for (int j = 0; j < 4; ++j)
        lpbuf[(g * 4 + j) * 1024 + n_base + nt * 16 + cl] = acc[h][nt][j] - logz[h][j];
    __syncthreads();
    const int tot = 16 * S;
    for (int idx = tid; idx < tot; idx += 512) {
      int r = idx / S;
      int s = idx - r * S;
      long m = row0 + h * 16 + r;
      if (m < M) {
        int bb = (int)(m % B);
        int lab = (s & 1) ? targets[bb * L + (s >> 1)] : 0;
        lp_ext[m * (long)S + s] = lpbuf[r * 1024 + lab];
      }
    }
  }
}

// ---------------------------------------------------------------------------
// CTC forward scan: one block per batch element, one thread per lattice state,
// with next-timestep lp prefetch.
// ---------------------------------------------------------------------------
__global__ __launch_bounds__(512) void ctc_kernel(
    const float* __restrict__ lp,  // (T,B,S)
    const int* __restrict__ targets, const int* __restrict__ inlens,
    const int* __restrict__ tlens, float* __restrict__ partial,
    int T, int B, int L, int S)
{
  __shared__ float al[2][512];
  __shared__ float lb_sh, ll_sh;
  const int b = blockIdx.x;
  const int s = threadIdx.x;
  const int inlen = inlens[b];
  const int tlen = tlens[b];
  const int send = 2 * tlen;
  if (threadIdx.x == 0) { lb_sh = NEGF; ll_sh = NEGF; }
  const bool active = (s < S);

  bool skip = false;
  if (active && (s & 1)) {
    int lab = targets[b * L + (s >> 1)];
    if (s >= 3) skip = (lab != 0) && (lab != targets[b * L + (s >> 1) - 1]);
  }
  const float* lpb = lp + (long)b * S;
  const long strideT = (long)B * S;

  if (active) {
    float v0 = (s <= 1) ? lpb[s] : NEGF;
    al[0][s] = v0;
    if (inlen == 1) {
      if (s == send) lb_sh = v0;
      else if (s == send - 1) ll_sh = v0;
    }
  }
  __syncthreads();

  float lpv_next = (active && T > 1) ? lpb[strideT + s] : 0.f;
  int p = 0;
  for (int t = 1; t < T; ++t) {
    float lpv = lpv_next;
    if (active && t + 1 < T) lpv_next = lpb[(long)(t + 1) * strideT + s];
    if (active) {
      float a0 = al[p][s];
      float a1 = (s >= 1) ? al[p][s - 1] : NEGF;
      float a2 = skip ? al[p][s - 2] : NEGF;
      float m = fmaxf(a0, fmaxf(a1, a2));
      float nv = m + logf(expf(a0 - m) + expf(a1 - m) + expf(a2 - m)) + lpv;
      al[p ^ 1][s] = nv;
      if (t == inlen - 1) {
        if (s == send) lb_sh = nv;
        else if (s == send - 1) ll_sh = nv;
      }
    }
    p ^= 1;
    __syncthreads();
  }

  if (threadIdx.x == 0) {
    float lb = lb_sh, ll = ll_sh;
    float mx = fmaxf(lb, ll);
    float loss = -(mx + logf(expf(lb - mx) + expf(ll - mx)));
    if (!(loss <= 1e29f)) loss = 0.f;  // zero_infinity (also catches NaN)
    partial[b] = loss / (float)tlen;
  }
}

__global__ void reduce_kernel(const float* __restrict__ partial,
                              float* __restrict__ out, int B)
{
  int lane = threadIdx.x;
  float v = (lane < B) ? partial[lane] : 0.f;
#pragma unroll
  for (int off = 32; off; off >>= 1) v += __shfl_xor(v, off);
  if (lane == 0) out[0] = v / (float)B;
}

// ---------------------------------------------------------------------------
extern "C" void kernel_launch(void* const* d_in, const int* in_sizes, int n_in,
                              void* d_out, int out_size, void* d_ws, size_t ws_size,
                              hipStream_t stream) {
  const float* enc = (const float*)d_in[0];
  const float* Wp  = (const float*)d_in[1];
  const float* bp  = (const float*)d_in[2];
  const float* Wt  = (const float*)d_in[3];
  const float* btr = (const float*)d_in[4];
  const float* lng = (const float*)d_in[5];
  const float* lnb = (const float*)d_in[6];
  const float* Wd  = (const float*)d_in[7];
  const float* bd  = (const float*)d_in[8];
  const int* tgt   = (const int*)d_in[9];
  const int* inl   = (const int*)d_in[10];
  const int* tll   = (const int*)d_in[11];

  const int D = in_sizes[2];              // 768
  const int V = in_sizes[8];              // 1024
  const int B = in_sizes[10];             // 32
  const int L = in_sizes[9] / B;          // 150
  const long M = (long)in_sizes[0] / D;   // T*B = 64000
  const int T = (int)(M / B);             // 2000
  const int S = 2 * L + 1;                // 301

  char* wsb = (char*)d_ws;
  size_t off = 0;
  auto alloc = [&](size_t bytes) { char* p = wsb + off; off += (bytes + 255) & ~(size_t)255; return p; };
  unsigned short* encb = (unsigned short*)alloc((size_t)M * D * 2);
  unsigned short* X1b  = (unsigned short*)alloc((size_t)M * D * 2);
  unsigned short* X2b  = (unsigned short*)alloc((size_t)M * D * 2);
  float* LP            = (float*)alloc((size_t)M * S * 4);
  unsigned short* WpT  = (unsigned short*)alloc((size_t)D * D * 2);
  unsigned short* WtT  = (unsigned short*)alloc((size_t)D * D * 2);
  unsigned short* WdT  = (unsigned short*)alloc((size_t)D * V * 2);
  float* partial       = (float*)alloc(256);

  // weight transpose+cvt (tiny)
  cvt_wt_kernel<<<dim3(D / 32, D / 32), dim3(32, 8), 0, stream>>>(Wp, WpT, D, D);
  cvt_wt_kernel<<<dim3(D / 32, D / 32), dim3(32, 8), 0, stream>>>(Wt, WtT, D, D);
  cvt_wt_kernel<<<dim3(V / 32, D / 32), dim3(32, 8), 0, stream>>>(Wd, WdT, D, V);
  // activation cvt
  cvt_enc_kernel<<<2048, 256, 0, stream>>>(enc, encb, (long)M * D / 4);

  const int grid = (int)((M + 31) / 32);
  const size_t smem12 = (size_t)32 * (768 + 8) * 2;  // 49664
  gemm_bf16_kernel<768, 6, 0><<<grid, 512, smem12, stream>>>(encb, WpT, bp, X1b, M);
  gemm_bf16_kernel<768, 6, 1><<<grid, 512, smem12, stream>>>(X1b, WtT, btr, X2b, M);
  ln_bf16_kernel<768><<<(int)((M + 3) / 4), 256, 0, stream>>>(X2b, lng, lnb, M);
  gemm3_bf16_kernel<768><<<grid, 512, 65536, stream>>>(X2b, WdT, bd, tgt, LP, M, B, L, S);

  const int cthreads = ((S + 63) / 64) * 64;
  ctc_kernel<<<B, cthreads, 0, stream>>>(LP, tgt, inl, tll, partial, T, B, L, S);
  reduce_kernel<<<1, 64, 0, stream>>>(partial, (float*)d_out, B);
}